// Round 19
// baseline (90.824 us; speedup 1.0000x reference)
//
#include <hip/hip_runtime.h>
#include <stdint.h>

typedef __bf16 bf16x8 __attribute__((ext_vector_type(8)));
typedef float  f32x4  __attribute__((ext_vector_type(4)));
typedef float  f32x16 __attribute__((ext_vector_type(16)));

#define MFMA(a,b,c)   __builtin_amdgcn_mfma_f32_16x16x32_bf16((a),(b),(c),0,0,0)
#define MFMA32(a,b,c) __builtin_amdgcn_mfma_f32_32x32x16_bf16((a),(b),(c),0,0,0)

// float -> bf16 bits, round-to-nearest-even (inputs finite)
__device__ __forceinline__ short f2b(float x) {
  uint32_t u = __float_as_uint(x);
  uint32_t r = (u + 0x7fffu + ((u >> 16) & 1u)) >> 16;
  return (short)r;
}

__device__ __forceinline__ uint32_t cvtpk(float lo, float hi) {
  uint32_t w;
  asm("v_cvt_pk_bf16_f32 %0, %1, %2" : "=v"(w) : "v"(lo), "v"(hi));
  return w;
}

// global(16B per lane) -> LDS, dest = wave-uniform base + lane*16
__device__ __forceinline__ void glds16(const void* g, void* l) {
  __builtin_amdgcn_global_load_lds(
      (const __attribute__((address_space(1))) void*)(uintptr_t)g,
      (__attribute__((address_space(3))) void*)(uintptr_t)l, 16, 0, 0);
}

// ---------------- prep: weights->bf16, rel^T, BN constants ----------------
__global__ void k_prep(const float* __restrict__ w1, const float* __restrict__ wq,
                       const float* __restrict__ wk, const float* __restrict__ wv,
                       const float* __restrict__ w2,
                       const float* __restrict__ relh, const float* __restrict__ relw,
                       const float* __restrict__ g1, const float* __restrict__ b1,
                       const float* __restrict__ m1, const float* __restrict__ v1,
                       const float* __restrict__ g2, const float* __restrict__ b2,
                       const float* __restrict__ m2, const float* __restrict__ v2,
                       short* __restrict__ w1b, short* __restrict__ wqb,
                       short* __restrict__ wkb, short* __restrict__ wvb,
                       short* __restrict__ w2b, short* __restrict__ rhT,
                       short* __restrict__ rwT, float* __restrict__ bnc) {
  int i = blockIdx.x * 256 + threadIdx.x;
  if (i < 32768) { w1b[i] = f2b(w1[i]); return; }
  i -= 32768;
  if (i < 16384) { wqb[i] = f2b(wq[i]); return; }
  i -= 16384;
  if (i < 16384) { wkb[i] = f2b(wk[i]); return; }
  i -= 16384;
  if (i < 16384) { wvb[i] = f2b(wv[i]); return; }
  i -= 16384;
  if (i < 32768) { w2b[i] = f2b(w2[i]); return; }
  i -= 32768;
  if (i < 4096) { int h = i >> 7, c = i & 127; rhT[i] = f2b(relh[c * 32 + h]); return; }
  i -= 4096;
  if (i < 4096) { int w = i >> 7, c = i & 127; rwT[i] = f2b(relw[c * 32 + w]); return; }
  i -= 4096;
  if (i < 128) { float s = g1[i] * rsqrtf(v1[i] + 1e-5f); bnc[i] = s; bnc[128 + i] = b1[i] - m1[i] * s; return; }
  i -= 128;
  if (i < 256) { float s = g2[i] * rsqrtf(v2[i] + 1e-5f); bnc[256 + i] = s; bnc[512 + i] = b2[i] - m2[i] * s; return; }
}

// ---------------- K1: fused conv1 + qkv + U/W (v2: q last, X1 reused as q tile -> 32.7KB LDS) ----------------
__launch_bounds__(256)
__global__ void k_cq(const float* __restrict__ x, const short* __restrict__ w1b,
                     const short* __restrict__ wqb, const short* __restrict__ wkb,
                     const short* __restrict__ wvb, const float* __restrict__ bnc,
                     const float* __restrict__ bq, const float* __restrict__ bk,
                     const float* __restrict__ bv,
                     const short* __restrict__ rhT, const short* __restrict__ rwT,
                     short* __restrict__ qT, short* __restrict__ kT,
                     short* __restrict__ vv, float* __restrict__ Ug,
                     float* __restrict__ Wg) {
  __shared__ __align__(16) short Al[128 * 40];    // 10240 B
  __shared__ __align__(16) short Bl[64 * 40];     // 5120 B
  __shared__ __align__(16) short X1[64 * 136];    // 17408 B  (x1 tile; reused as q tile at the end)
  const int bx = blockIdx.x;
  const int b = bx >> 4;
  const int n0 = (bx & 15) << 6;
  const int tid = threadIdx.x;
  const int wid = tid >> 6, lane = tid & 63;
  const int wr = wid >> 1, wc = wid & 1;
  const int cpr = lane & 15, g = lane >> 4;
  const int rl = lane & 31, hi2 = lane >> 5;
  const float* xb = x + (size_t)b * (256 * 1024);

  // ---- phase 1: conv1 (M=128, K=256, N=64) ----
  {
    f32x4 acc[4][2] = {};
    for (int kk = 0; kk < 8; ++kk) {
#pragma unroll
      for (int it = 0; it < 2; ++it) {
        int f = tid + it * 256;
        int row = f >> 2, c8 = f & 3;
        *reinterpret_cast<uint4*>(&Al[row * 40 + c8 * 8]) =
            *reinterpret_cast<const uint4*>(&w1b[row * 256 + kk * 32 + c8 * 8]);
      }
#pragma unroll
      for (int it = 0; it < 2; ++it) {
        int f = tid + it * 256;
        int ci = f >> 4, c4 = f & 15;
        float4 v4 = *reinterpret_cast<const float4*>(&xb[(size_t)(kk * 32 + ci) * 1024 + n0 + c4 * 4]);
        int nb = c4 * 4;
        Bl[(nb + 0) * 40 + ci] = f2b(v4.x);
        Bl[(nb + 1) * 40 + ci] = f2b(v4.y);
        Bl[(nb + 2) * 40 + ci] = f2b(v4.z);
        Bl[(nb + 3) * 40 + ci] = f2b(v4.w);
      }
      __syncthreads();
      bf16x8 af[4], bfr[2];
#pragma unroll
      for (int mf = 0; mf < 4; ++mf)
        af[mf] = *reinterpret_cast<const bf16x8*>(&Al[(wr * 64 + mf * 16 + cpr) * 40 + g * 8]);
#pragma unroll
      for (int nf = 0; nf < 2; ++nf)
        bfr[nf] = *reinterpret_cast<const bf16x8*>(&Bl[(wc * 32 + nf * 16 + cpr) * 40 + g * 8]);
#pragma unroll
      for (int mf = 0; mf < 4; ++mf)
#pragma unroll
        for (int nf = 0; nf < 2; ++nf)
          acc[mf][nf] = MFMA(af[mf], bfr[nf], acc[mf][nf]);
      __syncthreads();
    }
#pragma unroll
    for (int mf = 0; mf < 4; ++mf) {
      int m0 = wr * 64 + mf * 16 + g * 4;
#pragma unroll
      for (int nf = 0; nf < 2; ++nf) {
        int nl = wc * 32 + nf * 16 + cpr;
        union { short s[4]; uint2 u; } pk;
#pragma unroll
        for (int r = 0; r < 4; ++r) {
          int c = m0 + r;
          float z = acc[mf][nf][r] * bnc[c] + bnc[128 + c];
          pk.s[r] = f2b(z / (1.f + __expf(-z)));
        }
        *reinterpret_cast<uint2*>(&X1[nl * 136 + m0]) = pk.u;
      }
    }
  }
  __syncthreads();

  // ---- phase 2: v/k/q GEMMs (q LAST so X1 can be recycled as the q tile) ----
  for (int which = 0; which < 3; ++which) {
    const short* W = which == 0 ? wvb : which == 1 ? wkb : wqb;
    const float* bias = which == 0 ? bv : which == 1 ? bk : bq;
    f32x4 acc[4][2] = {};
    for (int kk = 0; kk < 4; ++kk) {
#pragma unroll
      for (int it = 0; it < 2; ++it) {
        int f = tid + it * 256;
        int row = f >> 2, c8 = f & 3;
        *reinterpret_cast<uint4*>(&Al[row * 40 + c8 * 8]) =
            *reinterpret_cast<const uint4*>(&W[row * 128 + kk * 32 + c8 * 8]);
      }
      __syncthreads();
      bf16x8 af[4], bfr[2];
#pragma unroll
      for (int mf = 0; mf < 4; ++mf)
        af[mf] = *reinterpret_cast<const bf16x8*>(&Al[(wr * 64 + mf * 16 + cpr) * 40 + g * 8]);
#pragma unroll
      for (int nf = 0; nf < 2; ++nf)
        bfr[nf] = *reinterpret_cast<const bf16x8*>(&X1[(wc * 32 + nf * 16 + cpr) * 136 + kk * 32 + g * 8]);
#pragma unroll
      for (int mf = 0; mf < 4; ++mf)
#pragma unroll
        for (int nf = 0; nf < 2; ++nf)
          acc[mf][nf] = MFMA(af[mf], bfr[nf], acc[mf][nf]);
      __syncthreads();   // also guarantees all X1 reads done before which==2 epilogue overwrites it
    }
#pragma unroll
    for (int mf = 0; mf < 4; ++mf) {
      int m0 = wr * 64 + mf * 16 + g * 4;
#pragma unroll
      for (int nf = 0; nf < 2; ++nf) {
        int n = n0 + wc * 32 + nf * 16 + cpr;
        int nl = wc * 32 + nf * 16 + cpr;
        if (which == 0) {
#pragma unroll
          for (int r = 0; r < 4; ++r) {
            int c = m0 + r;
            vv[((size_t)b * 128 + c) * 1024 + n] = f2b(acc[mf][nf][r] + bias[c]);
          }
        } else {
          union { short s4[4]; uint2 u; } pk;
#pragma unroll
          for (int r = 0; r < 4; ++r)
            pk.s4[r] = f2b(acc[mf][nf][r] + bias[m0 + r]);
          if (which == 1) {
            *reinterpret_cast<uint2*>(&kT[((size_t)b * 1024 + n) * 128 + m0]) = pk.u;
          } else {
            *reinterpret_cast<uint2*>(&qT[((size_t)b * 1024 + n) * 128 + m0]) = pk.u;
            *reinterpret_cast<uint2*>(&X1[nl * 136 + m0]) = pk.u;   // recycle X1 as q tile
          }
        }
      }
    }
  }
  __syncthreads();   // q tile complete in X1

  // ---- U = rel_h^T q, W = rel_w^T q for this block's 64 columns ----
  // Swapped operands: lane holds h = rl (D cols), rows = j-local (cregs).
  {
    const int sel = wid >> 1, nh = wid & 1;
    const short* R = sel ? rwT : rhT;
    float* Og = sel ? Wg : Ug;
    f32x16 d = {};
#pragma unroll
    for (int ks = 0; ks < 8; ++ks) {
      bf16x8 aq = *reinterpret_cast<const bf16x8*>(&X1[(nh * 32 + rl) * 136 + ks * 16 + hi2 * 8]);
      bf16x8 br = *reinterpret_cast<const bf16x8*>(&R[(size_t)rl * 128 + ks * 16 + hi2 * 8]);
      d = MFMA32(aq, br, d);
    }
#pragma unroll
    for (int q2 = 0; q2 < 4; ++q2) {
      f32x4 v4 = { d[4 * q2 + 0], d[4 * q2 + 1], d[4 * q2 + 2], d[4 * q2 + 3] };
      *reinterpret_cast<f32x4*>(&Og[((size_t)b * 32 + rl) * 1024 + n0 + nh * 32 + q2 * 8 + hi2 * 4]) = v4;
    }
  }
}

// ---------------- K2: flash attention (K=128 QK + additive U/W pos) + fused conv2 (R18-exact) ----------------
__launch_bounds__(512, 1)
__global__ void k_attn(const short* __restrict__ qT, const short* __restrict__ kT,
                       const short* __restrict__ vv, const float* __restrict__ Ug,
                       const float* __restrict__ Wg,
                       const short* __restrict__ w2b, const float* __restrict__ bnc,
                       const float* __restrict__ x, float* __restrict__ out) {
  __shared__ __align__(16) char smem[100864];
  short* KhB0 = (short*)smem;                      // 16K
  short* KhB1 = (short*)(smem + 16384);            // 16K
  short* VtB0 = (short*)(smem + 32768);            // 16K
  short* VtB1 = (short*)(smem + 49152);            // 16K
  float*    Obuf  = (float*)smem;                  // epilogue: 128x129 f32 (66048 B)
  uint16_t* ObufB = (uint16_t*)(smem + 66048);     // epilogue: 128x128 bf16 swizzled (32K)
  float*    mlf   = (float*)(smem + 98816);        // 2K

  const int bx0 = blockIdx.x;
  const int lbx = ((bx0 & 7) << 5) | (bx0 >> 3);
  const int b  = lbx >> 3;
  const int i0 = (lbx & 7) << 7;
  const int tid = threadIdx.x;
  const int wid = tid >> 6, lane = tid & 63;
  const int rl = lane & 31, hi = lane >> 5;
  const int jh = wid >> 2, iq = wid & 3;
  const size_t bN = (size_t)b * 1024;
  const int hI = ((lbx & 7) << 2) + iq;            // h(i) wave-uniform; w(i) = rl

  const short* srcK[2];
  const short* srcV[2];
#pragma unroll
  for (int it = 0; it < 2; ++it) {
    int gq = it * 512 + tid;
    int row = gq >> 4, p = gq & 15;
    int l = p ^ (row & 7);
    srcK[it] = &kT[(bN + row) * 128 + l * 8];
  }
#pragma unroll
  for (int it = 0; it < 2; ++it) {
    int gq = it * 512 + tid;
    int c = gq >> 3, p = gq & 7;
    int l = p ^ (c & 7);
    srcV[it] = &vv[((size_t)b * 128 + c) * 1024 + l * 8];
  }
#pragma unroll
  for (int it = 0; it < 2; ++it) glds16(srcK[it], &KhB0[(it * 512 + wid * 64) * 8]);
#pragma unroll
  for (int it = 0; it < 2; ++it) glds16(srcV[it], &VtB0[(it * 512 + wid * 64) * 8]);

  bf16x8 qf[8];
  {
    const int irow = i0 + iq * 32 + rl;
#pragma unroll
    for (int ks = 0; ks < 8; ++ks)
      qf[ks] = *reinterpret_cast<const bf16x8*>(&qT[(bN + irow) * 128 + ks * 16 + hi * 8]);
  }
  __syncthreads();

  f32x16 oacc[4] = {};
  float mrow = -3e38f, lrow = 0.f;
  const float* Urow = &Ug[((size_t)b * 32 + hI) * 1024 + (jh << 5) + (hi << 2)];
  const float* Wrow = &Wg[((size_t)b * 32 + rl) * 1024 + (jh << 5) + (hi << 2)];

  for (int jt = 0; jt < 16; ++jt) {
    const int cur = jt & 1;
    f32x4 u4[4], w4[4];
#pragma unroll
    for (int g2 = 0; g2 < 4; ++g2) {
      u4[g2] = *reinterpret_cast<const f32x4*>(&Urow[(jt << 6) + g2 * 8]);
      w4[g2] = *reinterpret_cast<const f32x4*>(&Wrow[(jt << 6) + g2 * 8]);
    }
    if (jt < 15) {
      short* KhN = cur ? KhB0 : KhB1;
      short* VtN = cur ? VtB0 : VtB1;
#pragma unroll
      for (int it = 0; it < 2; ++it)
        glds16(srcK[it] + ((jt + 1) << 13), &KhN[(it * 512 + wid * 64) * 8]);
#pragma unroll
      for (int it = 0; it < 2; ++it)
        glds16(srcV[it] + ((jt + 1) << 6), &VtN[(it * 512 + wid * 64) * 8]);
    }
    const short* KhC = cur ? KhB1 : KhB0;
    const short* VtC = cur ? VtB1 : VtB0;

    f32x16 s0 = {}, s1 = {};
    {
      const int rb = (jh * 32 + rl) * 128;
      __builtin_amdgcn_s_setprio(1);
#pragma unroll
      for (int ks = 0; ks < 8; ++ks) {
        int p = ((ks << 1) | hi) ^ (rl & 7);
        bf16x8 kf = *reinterpret_cast<const bf16x8*>(&KhC[rb + p * 8]);
        if (ks & 1) s1 = MFMA32(kf, qf[ks], s1);
        else        s0 = MFMA32(kf, qf[ks], s0);
      }
      __builtin_amdgcn_s_setprio(0);
    }
    float t[16];
#pragma unroll
    for (int r = 0; r < 16; ++r)
      t[r] = s0[r] + s1[r] + u4[r >> 2][r & 3] + w4[r >> 2][r & 3];
    float mx = t[0];
#pragma unroll
    for (int r = 1; r < 16; ++r) mx = fmaxf(mx, t[r]);
    mx = fmaxf(mx, __shfl_xor(mx, 32));
    float pr[16];
    float ps = 0.f;
    if (__all(mx <= mrow + 8.f)) {   // defer-max
#pragma unroll
      for (int r = 0; r < 16; ++r) { pr[r] = __expf(t[r] - mrow); ps += pr[r]; }
      ps += __shfl_xor(ps, 32);
      lrow += ps;
    } else {
      float mnew = fmaxf(mrow, mx);
      float sc = __expf(mrow - mnew);
#pragma unroll
      for (int r = 0; r < 16; ++r) { pr[r] = __expf(t[r] - mnew); ps += pr[r]; }
      ps += __shfl_xor(ps, 32);
      lrow = lrow * sc + ps;
      mrow = mnew;
#pragma unroll
      for (int ct = 0; ct < 4; ++ct)
#pragma unroll
        for (int r = 0; r < 16; ++r) oacc[ct][r] *= sc;
    }
    uint32_t own[8], rcv[8];
#pragma unroll
    for (int idx = 0; idx < 8; ++idx) own[idx] = cvtpk(pr[2 * idx], pr[2 * idx + 1]);
#pragma unroll
    for (int idx = 0; idx < 8; ++idx) rcv[idx] = __shfl_xor((int)own[idx], 32);
#pragma unroll
    for (int js = 0; js < 2; ++js) {
      union { uint32_t u[4]; bf16x8 v; } pa;
      pa.u[0] = hi ? rcv[4 * js + 2] : own[4 * js + 0];
      pa.u[1] = hi ? rcv[4 * js + 3] : own[4 * js + 1];
      pa.u[2] = hi ? own[4 * js + 2] : rcv[4 * js + 0];
      pa.u[3] = hi ? own[4 * js + 3] : rcv[4 * js + 1];
      __builtin_amdgcn_s_setprio(1);
#pragma unroll
      for (int ct = 0; ct < 4; ++ct) {
        int c = ct * 32 + rl;
        int p = ((jh << 2) | (js << 1) | hi) ^ (rl & 7);
        bf16x8 vf = *reinterpret_cast<const bf16x8*>(&VtC[c * 64 + p * 8]);
        oacc[ct] = MFMA32(vf, pa.v, oacc[ct]);
      }
      __builtin_amdgcn_s_setprio(0);
    }
    __syncthreads();
  }

  // ---- merge m/l across j-halves ----
  if (lane < 32) {
    mlf[wid * 64 + rl]      = mrow;
    mlf[wid * 64 + 32 + rl] = lrow;
  }
  __syncthreads();
  float scl;
  {
    const int pid = wid ^ 4;
    float mp = mlf[pid * 64 + rl];
    float lp = mlf[pid * 64 + 32 + rl];
    float M  = fmaxf(mrow, mp);
    float f  = __expf(mrow - M);
    float fp = __expf(mp - M);
    scl = f / (lrow * f + lp * fp);
  }
  bf16x8 af2[8];
#pragma unroll
  for (int ks = 0; ks < 8; ++ks)
    af2[ks] = *reinterpret_cast<const bf16x8*>(&w2b[(size_t)(wid * 32 + rl) * 128 + ks * 16 + hi * 8]);
  __syncthreads();

  const int row = iq * 32 + rl;
  if (jh == 0) {
#pragma unroll
    for (int ct = 0; ct < 4; ++ct)
#pragma unroll
      for (int r = 0; r < 16; ++r) {
        int c = ct * 32 + (r & 3) + 8 * (r >> 2) + 4 * hi;
        Obuf[row * 129 + c] = oacc[ct][r] * scl;
      }
  }
  __syncthreads();
  if (jh == 1) {
    uint32_t* OW = (uint32_t*)ObufB;
#pragma unroll
    for (int ct = 0; ct < 4; ++ct) {
      float mg[16];
#pragma unroll
      for (int r = 0; r < 16; ++r) {
        int c = ct * 32 + (r & 3) + 8 * (r >> 2) + 4 * hi;
        mg[r] = Obuf[row * 129 + c] + oacc[ct][r] * scl;
      }
#pragma unroll
      for (int m = 0; m < 8; ++m) {
        int c0 = ct * 32 + ((2 * m) & 3) + 8 * ((2 * m) >> 2) + 4 * hi;
        int gI = c0 >> 3, wo = (c0 & 7) >> 1;
        int gS = gI ^ (row & 15);
        OW[row * 64 + gS * 4 + wo] = cvtpk(mg[2 * m], mg[2 * m + 1]);
      }
    }
  }
  __syncthreads();

  f32x16 a2[4] = {};
#pragma unroll
  for (int it = 0; it < 4; ++it) {
    const int r2 = it * 32 + rl;
    __builtin_amdgcn_s_setprio(1);
#pragma unroll
    for (int ks = 0; ks < 8; ++ks) {
      int gS = ((ks << 1) | hi) ^ (r2 & 15);
      bf16x8 bf = *reinterpret_cast<const bf16x8*>(&ObufB[r2 * 128 + gS * 8]);
      a2[it] = MFMA32(af2[ks], bf, a2[it]);
    }
    __builtin_amdgcn_s_setprio(0);
  }
  float bsc[16], bsh[16];
#pragma unroll
  for (int r = 0; r < 16; ++r) {
    int co = wid * 32 + (r & 3) + 8 * (r >> 2) + 4 * hi;
    bsc[r] = bnc[256 + co];
    bsh[r] = bnc[512 + co];
  }
#pragma unroll
  for (int it = 0; it < 4; ++it) {
#pragma unroll
    for (int r = 0; r < 16; ++r) {
      int co = wid * 32 + (r & 3) + 8 * (r >> 2) + 4 * hi;
      size_t idx = ((size_t)b * 256 + co) * 1024 + i0 + it * 32 + rl;
      float y = a2[it][r] * bsc[r] + bsh[r];
      out[idx] = x[idx] + y / (1.f + __expf(-y));
    }
  }
}

// ---------------- host ----------------
extern "C" void kernel_launch(void* const* d_in, const int* in_sizes, int n_in,
                              void* d_out, int out_size, void* d_ws, size_t ws_size,
                              hipStream_t stream) {
  (void)in_sizes; (void)n_in; (void)out_size; (void)ws_size;
  const float* x    = (const float*)d_in[0];
  const float* w1   = (const float*)d_in[1];
  const float* g1   = (const float*)d_in[2];
  const float* b1   = (const float*)d_in[3];
  const float* m1   = (const float*)d_in[4];
  const float* v1   = (const float*)d_in[5];
  const float* wq   = (const float*)d_in[6];
  const float* bq   = (const float*)d_in[7];
  const float* wk   = (const float*)d_in[8];
  const float* bk   = (const float*)d_in[9];
  const float* wv   = (const float*)d_in[10];
  const float* bv   = (const float*)d_in[11];
  const float* relh = (const float*)d_in[12];
  const float* relw = (const float*)d_in[13];
  const float* w2   = (const float*)d_in[14];
  const float* g2   = (const float*)d_in[15];
  const float* b2   = (const float*)d_in[16];
  const float* m2   = (const float*)d_in[17];
  const float* v2   = (const float*)d_in[18];
  float* out = (float*)d_out;

  char* ws = (char*)d_ws;
  const size_t OFF_W1B  = 0;
  const size_t OFF_WQB  = 65536;
  const size_t OFF_WKB  = 98304;
  const size_t OFF_WVB  = 131072;
  const size_t OFF_W2B  = 163840;
  const size_t OFF_RHT  = 229376;                 // 8192
  const size_t OFF_RWT  = 237568;                 // 8192
  const size_t OFF_BN   = 491520;
  const size_t OFF_QT   = 494592;
  const size_t OFF_KT   = OFF_QT + 8388608;
  const size_t OFF_V    = OFF_KT + 8388608;
  const size_t OFF_UG   = OFF_V + 8388608;        // 4 MB
  const size_t OFF_WG   = OFF_UG + 4194304;       // 4 MB

  short* w1b  = (short*)(ws + OFF_W1B);
  short* wqb  = (short*)(ws + OFF_WQB);
  short* wkb  = (short*)(ws + OFF_WKB);
  short* wvb  = (short*)(ws + OFF_WVB);
  short* w2b  = (short*)(ws + OFF_W2B);
  short* rhT  = (short*)(ws + OFF_RHT);
  short* rwT  = (short*)(ws + OFF_RWT);
  float* bnc  = (float*)(ws + OFF_BN);
  short* qT   = (short*)(ws + OFF_QT);
  short* kT   = (short*)(ws + OFF_KT);
  short* vv   = (short*)(ws + OFF_V);
  float* Ug   = (float*)(ws + OFF_UG);
  float* Wg   = (float*)(ws + OFF_WG);

  k_prep<<<482, 256, 0, stream>>>(w1, wq, wk, wv, w2, relh, relw,
                                  g1, b1, m1, v1, g2, b2, m2, v2,
                                  w1b, wqb, wkb, wvb, w2b, rhT, rwT, bnc);
  k_cq<<<512, 256, 0, stream>>>(x, w1b, wqb, wkb, wvb, bnc, bq, bk, bv,
                                rhT, rwT, qT, kT, vv, Ug, Wg);
  k_attn<<<256, 512, 0, stream>>>(qT, kT, vv, Ug, Wg, w2b, bnc, x, out);
}

// Round 20
// 86.546 us; speedup vs baseline: 1.0494x; 1.0494x over previous
//
#include <hip/hip_runtime.h>
#include <stdint.h>

typedef __bf16 bf16x8 __attribute__((ext_vector_type(8)));
typedef float  f32x4  __attribute__((ext_vector_type(4)));
typedef float  f32x16 __attribute__((ext_vector_type(16)));

#define MFMA(a,b,c)   __builtin_amdgcn_mfma_f32_16x16x32_bf16((a),(b),(c),0,0,0)
#define MFMA32(a,b,c) __builtin_amdgcn_mfma_f32_32x32x16_bf16((a),(b),(c),0,0,0)

// float -> bf16 bits, round-to-nearest-even (inputs finite)
__device__ __forceinline__ short f2b(float x) {
  uint32_t u = __float_as_uint(x);
  uint32_t r = (u + 0x7fffu + ((u >> 16) & 1u)) >> 16;
  return (short)r;
}

__device__ __forceinline__ uint32_t cvtpk(float lo, float hi) {
  uint32_t w;
  asm("v_cvt_pk_bf16_f32 %0, %1, %2" : "=v"(w) : "v"(lo), "v"(hi));
  return w;
}

// global(16B per lane) -> LDS, dest = wave-uniform base + lane*16
__device__ __forceinline__ void glds16(const void* g, void* l) {
  __builtin_amdgcn_global_load_lds(
      (const __attribute__((address_space(1))) void*)(uintptr_t)g,
      (__attribute__((address_space(3))) void*)(uintptr_t)l, 16, 0, 0);
}

// ---------------- prep: weights->bf16, rel^T, BN constants ----------------
__global__ void k_prep(const float* __restrict__ w1, const float* __restrict__ wq,
                       const float* __restrict__ wk, const float* __restrict__ wv,
                       const float* __restrict__ w2,
                       const float* __restrict__ relh, const float* __restrict__ relw,
                       const float* __restrict__ g1, const float* __restrict__ b1,
                       const float* __restrict__ m1, const float* __restrict__ v1,
                       const float* __restrict__ g2, const float* __restrict__ b2,
                       const float* __restrict__ m2, const float* __restrict__ v2,
                       short* __restrict__ w1b, short* __restrict__ wqb,
                       short* __restrict__ wkb, short* __restrict__ wvb,
                       short* __restrict__ w2b, short* __restrict__ rhT,
                       short* __restrict__ rwT, float* __restrict__ bnc) {
  int i = blockIdx.x * 256 + threadIdx.x;
  if (i < 32768) { w1b[i] = f2b(w1[i]); return; }
  i -= 32768;
  if (i < 16384) { wqb[i] = f2b(wq[i]); return; }
  i -= 16384;
  if (i < 16384) { wkb[i] = f2b(wk[i]); return; }
  i -= 16384;
  if (i < 16384) { wvb[i] = f2b(wv[i]); return; }
  i -= 16384;
  if (i < 32768) { w2b[i] = f2b(w2[i]); return; }
  i -= 32768;
  if (i < 4096) { int h = i >> 7, c = i & 127; rhT[i] = f2b(relh[c * 32 + h]); return; }
  i -= 4096;
  if (i < 4096) { int w = i >> 7, c = i & 127; rwT[i] = f2b(relw[c * 32 + w]); return; }
  i -= 4096;
  if (i < 128) { float s = g1[i] * rsqrtf(v1[i] + 1e-5f); bnc[i] = s; bnc[128 + i] = b1[i] - m1[i] * s; return; }
  i -= 128;
  if (i < 256) { float s = g2[i] * rsqrtf(v2[i] + 1e-5f); bnc[256 + i] = s; bnc[512 + i] = b2[i] - m2[i] * s; return; }
}

// ---------------- K1: fused conv1 + qkv + U/W (R19-exact) ----------------
__launch_bounds__(256)
__global__ void k_cq(const float* __restrict__ x, const short* __restrict__ w1b,
                     const short* __restrict__ wqb, const short* __restrict__ wkb,
                     const short* __restrict__ wvb, const float* __restrict__ bnc,
                     const float* __restrict__ bq, const float* __restrict__ bk,
                     const float* __restrict__ bv,
                     const short* __restrict__ rhT, const short* __restrict__ rwT,
                     short* __restrict__ qT, short* __restrict__ kT,
                     short* __restrict__ vv, float* __restrict__ Ug,
                     float* __restrict__ Wg) {
  __shared__ __align__(16) short Al[128 * 40];
  __shared__ __align__(16) short Bl[64 * 40];
  __shared__ __align__(16) short X1[64 * 136];
  const int bx = blockIdx.x;
  const int b = bx >> 4;
  const int n0 = (bx & 15) << 6;
  const int tid = threadIdx.x;
  const int wid = tid >> 6, lane = tid & 63;
  const int wr = wid >> 1, wc = wid & 1;
  const int cpr = lane & 15, g = lane >> 4;
  const int rl = lane & 31, hi2 = lane >> 5;
  const float* xb = x + (size_t)b * (256 * 1024);

  {
    f32x4 acc[4][2] = {};
    for (int kk = 0; kk < 8; ++kk) {
#pragma unroll
      for (int it = 0; it < 2; ++it) {
        int f = tid + it * 256;
        int row = f >> 2, c8 = f & 3;
        *reinterpret_cast<uint4*>(&Al[row * 40 + c8 * 8]) =
            *reinterpret_cast<const uint4*>(&w1b[row * 256 + kk * 32 + c8 * 8]);
      }
#pragma unroll
      for (int it = 0; it < 2; ++it) {
        int f = tid + it * 256;
        int ci = f >> 4, c4 = f & 15;
        float4 v4 = *reinterpret_cast<const float4*>(&xb[(size_t)(kk * 32 + ci) * 1024 + n0 + c4 * 4]);
        int nb = c4 * 4;
        Bl[(nb + 0) * 40 + ci] = f2b(v4.x);
        Bl[(nb + 1) * 40 + ci] = f2b(v4.y);
        Bl[(nb + 2) * 40 + ci] = f2b(v4.z);
        Bl[(nb + 3) * 40 + ci] = f2b(v4.w);
      }
      __syncthreads();
      bf16x8 af[4], bfr[2];
#pragma unroll
      for (int mf = 0; mf < 4; ++mf)
        af[mf] = *reinterpret_cast<const bf16x8*>(&Al[(wr * 64 + mf * 16 + cpr) * 40 + g * 8]);
#pragma unroll
      for (int nf = 0; nf < 2; ++nf)
        bfr[nf] = *reinterpret_cast<const bf16x8*>(&Bl[(wc * 32 + nf * 16 + cpr) * 40 + g * 8]);
#pragma unroll
      for (int mf = 0; mf < 4; ++mf)
#pragma unroll
        for (int nf = 0; nf < 2; ++nf)
          acc[mf][nf] = MFMA(af[mf], bfr[nf], acc[mf][nf]);
      __syncthreads();
    }
#pragma unroll
    for (int mf = 0; mf < 4; ++mf) {
      int m0 = wr * 64 + mf * 16 + g * 4;
#pragma unroll
      for (int nf = 0; nf < 2; ++nf) {
        int nl = wc * 32 + nf * 16 + cpr;
        union { short s[4]; uint2 u; } pk;
#pragma unroll
        for (int r = 0; r < 4; ++r) {
          int c = m0 + r;
          float z = acc[mf][nf][r] * bnc[c] + bnc[128 + c];
          pk.s[r] = f2b(z / (1.f + __expf(-z)));
        }
        *reinterpret_cast<uint2*>(&X1[nl * 136 + m0]) = pk.u;
      }
    }
  }
  __syncthreads();

  for (int which = 0; which < 3; ++which) {
    const short* W = which == 0 ? wvb : which == 1 ? wkb : wqb;
    const float* bias = which == 0 ? bv : which == 1 ? bk : bq;
    f32x4 acc[4][2] = {};
    for (int kk = 0; kk < 4; ++kk) {
#pragma unroll
      for (int it = 0; it < 2; ++it) {
        int f = tid + it * 256;
        int row = f >> 2, c8 = f & 3;
        *reinterpret_cast<uint4*>(&Al[row * 40 + c8 * 8]) =
            *reinterpret_cast<const uint4*>(&W[row * 128 + kk * 32 + c8 * 8]);
      }
      __syncthreads();
      bf16x8 af[4], bfr[2];
#pragma unroll
      for (int mf = 0; mf < 4; ++mf)
        af[mf] = *reinterpret_cast<const bf16x8*>(&Al[(wr * 64 + mf * 16 + cpr) * 40 + g * 8]);
#pragma unroll
      for (int nf = 0; nf < 2; ++nf)
        bfr[nf] = *reinterpret_cast<const bf16x8*>(&X1[(wc * 32 + nf * 16 + cpr) * 136 + kk * 32 + g * 8]);
#pragma unroll
      for (int mf = 0; mf < 4; ++mf)
#pragma unroll
        for (int nf = 0; nf < 2; ++nf)
          acc[mf][nf] = MFMA(af[mf], bfr[nf], acc[mf][nf]);
      __syncthreads();
    }
#pragma unroll
    for (int mf = 0; mf < 4; ++mf) {
      int m0 = wr * 64 + mf * 16 + g * 4;
#pragma unroll
      for (int nf = 0; nf < 2; ++nf) {
        int n = n0 + wc * 32 + nf * 16 + cpr;
        int nl = wc * 32 + nf * 16 + cpr;
        if (which == 0) {
#pragma unroll
          for (int r = 0; r < 4; ++r) {
            int c = m0 + r;
            vv[((size_t)b * 128 + c) * 1024 + n] = f2b(acc[mf][nf][r] + bias[c]);
          }
        } else {
          union { short s4[4]; uint2 u; } pk;
#pragma unroll
          for (int r = 0; r < 4; ++r)
            pk.s4[r] = f2b(acc[mf][nf][r] + bias[m0 + r]);
          if (which == 1) {
            *reinterpret_cast<uint2*>(&kT[((size_t)b * 1024 + n) * 128 + m0]) = pk.u;
          } else {
            *reinterpret_cast<uint2*>(&qT[((size_t)b * 1024 + n) * 128 + m0]) = pk.u;
            *reinterpret_cast<uint2*>(&X1[nl * 136 + m0]) = pk.u;
          }
        }
      }
    }
  }
  __syncthreads();

  {
    const int sel = wid >> 1, nh = wid & 1;
    const short* R = sel ? rwT : rhT;
    float* Og = sel ? Wg : Ug;
    f32x16 d = {};
#pragma unroll
    for (int ks = 0; ks < 8; ++ks) {
      bf16x8 aq = *reinterpret_cast<const bf16x8*>(&X1[(nh * 32 + rl) * 136 + ks * 16 + hi2 * 8]);
      bf16x8 br = *reinterpret_cast<const bf16x8*>(&R[(size_t)rl * 128 + ks * 16 + hi2 * 8]);
      d = MFMA32(aq, br, d);
    }
#pragma unroll
    for (int q2 = 0; q2 < 4; ++q2) {
      f32x4 v4 = { d[4 * q2 + 0], d[4 * q2 + 1], d[4 * q2 + 2], d[4 * q2 + 3] };
      *reinterpret_cast<f32x4*>(&Og[((size_t)b * 32 + rl) * 1024 + n0 + nh * 32 + q2 * 8 + hi2 * 4]) = v4;
    }
  }
}

// ---------------- K2: flash attention (v8: 4-wave 64-row blocks, 2 blocks/CU, split conv2) ----------------
// 512 blocks x 256 thr, 4 waves = jh(2) x iq(2). Loop identical to R19 (1 barrier/jt,
// dbuf K/V, factorized pos). Epilogue: no O-merge — each jh half writes scaled bf16 O,
// conv2 accumulates W2@O0 + W2@O1 (linearity). LDS 66.5KB -> 2 blocks/CU.
__launch_bounds__(256, 2)
__global__ void k_attn(const short* __restrict__ qT, const short* __restrict__ kT,
                       const short* __restrict__ vv, const float* __restrict__ Ug,
                       const float* __restrict__ Wg,
                       const short* __restrict__ w2b, const float* __restrict__ bnc,
                       const float* __restrict__ x, float* __restrict__ out) {
  __shared__ __align__(16) char smem[66560];
  short* KhB0 = (short*)smem;                      // 16K
  short* KhB1 = (short*)(smem + 16384);            // 16K
  short* VtB0 = (short*)(smem + 32768);            // 16K
  short* VtB1 = (short*)(smem + 49152);            // 16K
  uint16_t* ObufB0 = (uint16_t*)smem;              // epilogue: [64][128] bf16 swizzled (16K)
  uint16_t* ObufB1 = (uint16_t*)(smem + 16384);    // epilogue: 16K
  float*    mlf    = (float*)(smem + 32768);       // epilogue: 1K

  const int bx0 = blockIdx.x;
  const int lbx = ((bx0 & 7) << 6) | (bx0 >> 3);   // bijective XCD swizzle (512 = 8*64)
  const int b  = lbx >> 4;
  const int i0 = (lbx & 15) << 6;
  const int tid = threadIdx.x;
  const int wid = tid >> 6, lane = tid & 63;
  const int rl = lane & 31, hi = lane >> 5;
  const int jh = wid >> 1, iq = wid & 1;
  const size_t bN = (size_t)b * 1024;
  const int hI = ((lbx & 15) << 1) + iq;           // h(i) wave-uniform; w(i) = rl

  const short* srcK[4];
  const short* srcV[4];
#pragma unroll
  for (int it = 0; it < 4; ++it) {
    int gq = it * 256 + tid;          // granule 0..1023 of K tile [64 rows][16 granules]
    int row = gq >> 4, p = gq & 15;
    int l = p ^ (row & 7);
    srcK[it] = &kT[(bN + row) * 128 + l * 8];
  }
#pragma unroll
  for (int it = 0; it < 4; ++it) {
    int gq = it * 256 + tid;          // granule 0..1023 of V tile [128 c][8 granules]
    int c = gq >> 3, p = gq & 7;
    int l = p ^ (c & 7);
    srcV[it] = &vv[((size_t)b * 128 + c) * 1024 + l * 8];
  }
#pragma unroll
  for (int it = 0; it < 4; ++it) glds16(srcK[it], &KhB0[(it * 256 + wid * 64) * 8]);
#pragma unroll
  for (int it = 0; it < 4; ++it) glds16(srcV[it], &VtB0[(it * 256 + wid * 64) * 8]);

  bf16x8 qf[8];
  {
    const int irow = i0 + iq * 32 + rl;
#pragma unroll
    for (int ks = 0; ks < 8; ++ks)
      qf[ks] = *reinterpret_cast<const bf16x8*>(&qT[(bN + irow) * 128 + ks * 16 + hi * 8]);
  }
  __syncthreads();

  f32x16 oacc[4] = {};
  float mrow = -3e38f, lrow = 0.f;
  const float* Urow = &Ug[((size_t)b * 32 + hI) * 1024 + (jh << 5) + (hi << 2)];
  const float* Wrow = &Wg[((size_t)b * 32 + rl) * 1024 + (jh << 5) + (hi << 2)];

  for (int jt = 0; jt < 16; ++jt) {
    const int cur = jt & 1;
    f32x4 u4[4], w4[4];
#pragma unroll
    for (int g2 = 0; g2 < 4; ++g2) {
      u4[g2] = *reinterpret_cast<const f32x4*>(&Urow[(jt << 6) + g2 * 8]);
      w4[g2] = *reinterpret_cast<const f32x4*>(&Wrow[(jt << 6) + g2 * 8]);
    }
    if (jt < 15) {
      short* KhN = cur ? KhB0 : KhB1;
      short* VtN = cur ? VtB0 : VtB1;
#pragma unroll
      for (int it = 0; it < 4; ++it)
        glds16(srcK[it] + ((jt + 1) << 13), &KhN[(it * 256 + wid * 64) * 8]);
#pragma unroll
      for (int it = 0; it < 4; ++it)
        glds16(srcV[it] + ((jt + 1) << 6), &VtN[(it * 256 + wid * 64) * 8]);
    }
    const short* KhC = cur ? KhB1 : KhB0;
    const short* VtC = cur ? VtB1 : VtB0;

    f32x16 s0 = {}, s1 = {};
    {
      const int rb = (jh * 32 + rl) * 128;
      __builtin_amdgcn_s_setprio(1);
#pragma unroll
      for (int ks = 0; ks < 8; ++ks) {
        int p = ((ks << 1) | hi) ^ (rl & 7);
        bf16x8 kf = *reinterpret_cast<const bf16x8*>(&KhC[rb + p * 8]);
        if (ks & 1) s1 = MFMA32(kf, qf[ks], s1);
        else        s0 = MFMA32(kf, qf[ks], s0);
      }
      __builtin_amdgcn_s_setprio(0);
    }
    float t[16];
#pragma unroll
    for (int r = 0; r < 16; ++r)
      t[r] = s0[r] + s1[r] + u4[r >> 2][r & 3] + w4[r >> 2][r & 3];
    float mx = t[0];
#pragma unroll
    for (int r = 1; r < 16; ++r) mx = fmaxf(mx, t[r]);
    mx = fmaxf(mx, __shfl_xor(mx, 32));
    float pr[16];
    float ps = 0.f;
    if (__all(mx <= mrow + 8.f)) {   // defer-max
#pragma unroll
      for (int r = 0; r < 16; ++r) { pr[r] = __expf(t[r] - mrow); ps += pr[r]; }
      ps += __shfl_xor(ps, 32);
      lrow += ps;
    } else {
      float mnew = fmaxf(mrow, mx);
      float sc = __expf(mrow - mnew);
#pragma unroll
      for (int r = 0; r < 16; ++r) { pr[r] = __expf(t[r] - mnew); ps += pr[r]; }
      ps += __shfl_xor(ps, 32);
      lrow = lrow * sc + ps;
      mrow = mnew;
#pragma unroll
      for (int ct = 0; ct < 4; ++ct)
#pragma unroll
        for (int r = 0; r < 16; ++r) oacc[ct][r] *= sc;
    }
    uint32_t own[8], rcv[8];
#pragma unroll
    for (int idx = 0; idx < 8; ++idx) own[idx] = cvtpk(pr[2 * idx], pr[2 * idx + 1]);
#pragma unroll
    for (int idx = 0; idx < 8; ++idx) rcv[idx] = __shfl_xor((int)own[idx], 32);
#pragma unroll
    for (int js = 0; js < 2; ++js) {
      union { uint32_t u[4]; bf16x8 v; } pa;
      pa.u[0] = hi ? rcv[4 * js + 2] : own[4 * js + 0];
      pa.u[1] = hi ? rcv[4 * js + 3] : own[4 * js + 1];
      pa.u[2] = hi ? own[4 * js + 2] : rcv[4 * js + 0];
      pa.u[3] = hi ? own[4 * js + 3] : rcv[4 * js + 1];
      __builtin_amdgcn_s_setprio(1);
#pragma unroll
      for (int ct = 0; ct < 4; ++ct) {
        int c = ct * 32 + rl;
        int p = ((jh << 2) | (js << 1) | hi) ^ (rl & 7);
        bf16x8 vf = *reinterpret_cast<const bf16x8*>(&VtC[c * 64 + p * 8]);
        oacc[ct] = MFMA32(vf, pa.v, oacc[ct]);
      }
      __builtin_amdgcn_s_setprio(0);
    }
    __syncthreads();
  }

  // ---- merge m/l only (O halves stay separate; conv2 is linear) ----
  if (lane < 32) {
    mlf[wid * 64 + rl]      = mrow;
    mlf[wid * 64 + 32 + rl] = lrow;
  }
  __syncthreads();
  float scl;
  {
    const int pid = wid ^ 2;
    float mp = mlf[pid * 64 + rl];
    float lp = mlf[pid * 64 + 32 + rl];
    float M  = fmaxf(mrow, mp);
    float f  = __expf(mrow - M);
    float fp = __expf(mp - M);
    scl = f / (lrow * f + lp * fp);
  }
  // conv2 A-frags: this wave's 64-co range (2 sub-blocks of 32)
  bf16x8 af2[2][8];
#pragma unroll
  for (int sub = 0; sub < 2; ++sub)
#pragma unroll
    for (int ks = 0; ks < 8; ++ks)
      af2[sub][ks] = *reinterpret_cast<const bf16x8*>(
          &w2b[(size_t)(wid * 64 + sub * 32 + rl) * 128 + ks * 16 + hi * 8]);
  __syncthreads();   // mlf reads done; Obuf overlay safe

  // ---- write scaled bf16 O-half (swizzled) ----
  {
    uint32_t* OW = (uint32_t*)(jh ? ObufB1 : ObufB0);
    const int row = iq * 32 + rl;
#pragma unroll
    for (int ct = 0; ct < 4; ++ct) {
#pragma unroll
      for (int m = 0; m < 8; ++m) {
        int c0 = ct * 32 + ((2 * m) & 3) + 8 * ((2 * m) >> 2) + 4 * hi;
        int gI = c0 >> 3, wo = (c0 & 7) >> 1;
        int gS = gI ^ (row & 15);
        OW[row * 64 + gS * 4 + wo] = cvtpk(oacc[ct][2 * m] * scl, oacc[ct][2 * m + 1] * scl);
      }
    }
  }
  __syncthreads();

  // ---- conv2 GEMM over both halves: co = wid*64+sub*32+creg, n = i0+it*32+rl ----
  f32x16 a2[2][2] = {};
#pragma unroll
  for (int it = 0; it < 2; ++it) {
    const int r2 = it * 32 + rl;
    __builtin_amdgcn_s_setprio(1);
#pragma unroll
    for (int ks = 0; ks < 8; ++ks) {
      int gS = ((ks << 1) | hi) ^ (r2 & 15);
      bf16x8 bf0 = *reinterpret_cast<const bf16x8*>(&ObufB0[r2 * 128 + gS * 8]);
      bf16x8 bf1 = *reinterpret_cast<const bf16x8*>(&ObufB1[r2 * 128 + gS * 8]);
      a2[0][it] = MFMA32(af2[0][ks], bf0, a2[0][it]);
      a2[1][it] = MFMA32(af2[1][ks], bf0, a2[1][it]);
      a2[0][it] = MFMA32(af2[0][ks], bf1, a2[0][it]);
      a2[1][it] = MFMA32(af2[1][ks], bf1, a2[1][it]);
    }
    __builtin_amdgcn_s_setprio(0);
  }
#pragma unroll
  for (int sub = 0; sub < 2; ++sub) {
    float bsc[16], bsh[16];
#pragma unroll
    for (int r = 0; r < 16; ++r) {
      int co = wid * 64 + sub * 32 + (r & 3) + 8 * (r >> 2) + 4 * hi;
      bsc[r] = bnc[256 + co];
      bsh[r] = bnc[512 + co];
    }
#pragma unroll
    for (int it = 0; it < 2; ++it) {
#pragma unroll
      for (int r = 0; r < 16; ++r) {
        int co = wid * 64 + sub * 32 + (r & 3) + 8 * (r >> 2) + 4 * hi;
        size_t idx = ((size_t)b * 256 + co) * 1024 + i0 + it * 32 + rl;
        float y = a2[sub][it][r] * bsc[r] + bsh[r];
        out[idx] = x[idx] + y / (1.f + __expf(-y));
      }
    }
  }
}

// ---------------- host ----------------
extern "C" void kernel_launch(void* const* d_in, const int* in_sizes, int n_in,
                              void* d_out, int out_size, void* d_ws, size_t ws_size,
                              hipStream_t stream) {
  (void)in_sizes; (void)n_in; (void)out_size; (void)ws_size;
  const float* x    = (const float*)d_in[0];
  const float* w1   = (const float*)d_in[1];
  const float* g1   = (const float*)d_in[2];
  const float* b1   = (const float*)d_in[3];
  const float* m1   = (const float*)d_in[4];
  const float* v1   = (const float*)d_in[5];
  const float* wq   = (const float*)d_in[6];
  const float* bq   = (const float*)d_in[7];
  const float* wk   = (const float*)d_in[8];
  const float* bk   = (const float*)d_in[9];
  const float* wv   = (const float*)d_in[10];
  const float* bv   = (const float*)d_in[11];
  const float* relh = (const float*)d_in[12];
  const float* relw = (const float*)d_in[13];
  const float* w2   = (const float*)d_in[14];
  const float* g2   = (const float*)d_in[15];
  const float* b2   = (const float*)d_in[16];
  const float* m2   = (const float*)d_in[17];
  const float* v2   = (const float*)d_in[18];
  float* out = (float*)d_out;

  char* ws = (char*)d_ws;
  const size_t OFF_W1B  = 0;
  const size_t OFF_WQB  = 65536;
  const size_t OFF_WKB  = 98304;
  const size_t OFF_WVB  = 131072;
  const size_t OFF_W2B  = 163840;
  const size_t OFF_RHT  = 229376;
  const size_t OFF_RWT  = 237568;
  const size_t OFF_BN   = 491520;
  const size_t OFF_QT   = 494592;
  const size_t OFF_KT   = OFF_QT + 8388608;
  const size_t OFF_V    = OFF_KT + 8388608;
  const size_t OFF_UG   = OFF_V + 8388608;
  const size_t OFF_WG   = OFF_UG + 4194304;

  short* w1b  = (short*)(ws + OFF_W1B);
  short* wqb  = (short*)(ws + OFF_WQB);
  short* wkb  = (short*)(ws + OFF_WKB);
  short* wvb  = (short*)(ws + OFF_WVB);
  short* w2b  = (short*)(ws + OFF_W2B);
  short* rhT  = (short*)(ws + OFF_RHT);
  short* rwT  = (short*)(ws + OFF_RWT);
  float* bnc  = (float*)(ws + OFF_BN);
  short* qT   = (short*)(ws + OFF_QT);
  short* kT   = (short*)(ws + OFF_KT);
  short* vv   = (short*)(ws + OFF_V);
  float* Ug   = (float*)(ws + OFF_UG);
  float* Wg   = (float*)(ws + OFF_WG);

  k_prep<<<482, 256, 0, stream>>>(w1, wq, wk, wv, w2, relh, relw,
                                  g1, b1, m1, v1, g2, b2, m2, v2,
                                  w1b, wqb, wkb, wvb, w2b, rhT, rwT, bnc);
  k_cq<<<512, 256, 0, stream>>>(x, w1b, wqb, wkb, wvb, bnc, bq, bk, bv,
                                rhT, rwT, qT, kT, vv, Ug, Wg);
  k_attn<<<512, 256, 0, stream>>>(qT, kT, vv, Ug, Wg, w2b, bnc, x, out);
}

// Round 21
// 86.077 us; speedup vs baseline: 1.0551x; 1.0054x over previous
//
#include <hip/hip_runtime.h>
#include <stdint.h>

typedef __bf16 bf16x8 __attribute__((ext_vector_type(8)));
typedef float  f32x4  __attribute__((ext_vector_type(4)));
typedef float  f32x16 __attribute__((ext_vector_type(16)));

#define MFMA(a,b,c)   __builtin_amdgcn_mfma_f32_16x16x32_bf16((a),(b),(c),0,0,0)
#define MFMA32(a,b,c) __builtin_amdgcn_mfma_f32_32x32x16_bf16((a),(b),(c),0,0,0)

#define LOG2E 1.44269504088896f

// float -> bf16 bits, round-to-nearest-even (inputs finite)
__device__ __forceinline__ short f2b(float x) {
  uint32_t u = __float_as_uint(x);
  uint32_t r = (u + 0x7fffu + ((u >> 16) & 1u)) >> 16;
  return (short)r;
}

__device__ __forceinline__ uint32_t cvtpk(float lo, float hi) {
  uint32_t w;
  asm("v_cvt_pk_bf16_f32 %0, %1, %2" : "=v"(w) : "v"(lo), "v"(hi));
  return w;
}

// native 2^x (v_exp_f32)
__device__ __forceinline__ float fexp2(float x) {
  float r;
  asm("v_exp_f32 %0, %1" : "=v"(r) : "v"(x));
  return r;
}

// global(16B per lane) -> LDS, dest = wave-uniform base + lane*16
__device__ __forceinline__ void glds16(const void* g, void* l) {
  __builtin_amdgcn_global_load_lds(
      (const __attribute__((address_space(1))) void*)(uintptr_t)g,
      (__attribute__((address_space(3))) void*)(uintptr_t)l, 16, 0, 0);
}

// ---------------- prep: weights->bf16, rel^T, BN constants ----------------
__global__ void k_prep(const float* __restrict__ w1, const float* __restrict__ wq,
                       const float* __restrict__ wk, const float* __restrict__ wv,
                       const float* __restrict__ w2,
                       const float* __restrict__ relh, const float* __restrict__ relw,
                       const float* __restrict__ g1, const float* __restrict__ b1,
                       const float* __restrict__ m1, const float* __restrict__ v1,
                       const float* __restrict__ g2, const float* __restrict__ b2,
                       const float* __restrict__ m2, const float* __restrict__ v2,
                       short* __restrict__ w1b, short* __restrict__ wqb,
                       short* __restrict__ wkb, short* __restrict__ wvb,
                       short* __restrict__ w2b, short* __restrict__ rhT,
                       short* __restrict__ rwT, float* __restrict__ bnc) {
  int i = blockIdx.x * 256 + threadIdx.x;
  if (i < 32768) { w1b[i] = f2b(w1[i]); return; }
  i -= 32768;
  if (i < 16384) { wqb[i] = f2b(wq[i]); return; }
  i -= 16384;
  if (i < 16384) { wkb[i] = f2b(wk[i]); return; }
  i -= 16384;
  if (i < 16384) { wvb[i] = f2b(wv[i]); return; }
  i -= 16384;
  if (i < 32768) { w2b[i] = f2b(w2[i]); return; }
  i -= 32768;
  if (i < 4096) { int h = i >> 7, c = i & 127; rhT[i] = f2b(relh[c * 32 + h]); return; }
  i -= 4096;
  if (i < 4096) { int w = i >> 7, c = i & 127; rwT[i] = f2b(relw[c * 32 + w]); return; }
  i -= 4096;
  if (i < 128) { float s = g1[i] * rsqrtf(v1[i] + 1e-5f); bnc[i] = s; bnc[128 + i] = b1[i] - m1[i] * s; return; }
  i -= 128;
  if (i < 256) { float s = g2[i] * rsqrtf(v2[i] + 1e-5f); bnc[256 + i] = s; bnc[512 + i] = b2[i] - m2[i] * s; return; }
}

// ---------------- K1: fused conv1 + qkv + U/W (q pre-scaled by log2(e)) ----------------
__launch_bounds__(256)
__global__ void k_cq(const float* __restrict__ x, const short* __restrict__ w1b,
                     const short* __restrict__ wqb, const short* __restrict__ wkb,
                     const short* __restrict__ wvb, const float* __restrict__ bnc,
                     const float* __restrict__ bq, const float* __restrict__ bk,
                     const float* __restrict__ bv,
                     const short* __restrict__ rhT, const short* __restrict__ rwT,
                     short* __restrict__ qT, short* __restrict__ kT,
                     short* __restrict__ vv, float* __restrict__ Ug,
                     float* __restrict__ Wg) {
  __shared__ __align__(16) short Al[128 * 40];
  __shared__ __align__(16) short Bl[64 * 40];
  __shared__ __align__(16) short X1[64 * 136];
  const int bx = blockIdx.x;
  const int b = bx >> 4;
  const int n0 = (bx & 15) << 6;
  const int tid = threadIdx.x;
  const int wid = tid >> 6, lane = tid & 63;
  const int wr = wid >> 1, wc = wid & 1;
  const int cpr = lane & 15, g = lane >> 4;
  const int rl = lane & 31, hi2 = lane >> 5;
  const float* xb = x + (size_t)b * (256 * 1024);

  {
    f32x4 acc[4][2] = {};
    for (int kk = 0; kk < 8; ++kk) {
#pragma unroll
      for (int it = 0; it < 2; ++it) {
        int f = tid + it * 256;
        int row = f >> 2, c8 = f & 3;
        *reinterpret_cast<uint4*>(&Al[row * 40 + c8 * 8]) =
            *reinterpret_cast<const uint4*>(&w1b[row * 256 + kk * 32 + c8 * 8]);
      }
#pragma unroll
      for (int it = 0; it < 2; ++it) {
        int f = tid + it * 256;
        int ci = f >> 4, c4 = f & 15;
        float4 v4 = *reinterpret_cast<const float4*>(&xb[(size_t)(kk * 32 + ci) * 1024 + n0 + c4 * 4]);
        int nb = c4 * 4;
        Bl[(nb + 0) * 40 + ci] = f2b(v4.x);
        Bl[(nb + 1) * 40 + ci] = f2b(v4.y);
        Bl[(nb + 2) * 40 + ci] = f2b(v4.z);
        Bl[(nb + 3) * 40 + ci] = f2b(v4.w);
      }
      __syncthreads();
      bf16x8 af[4], bfr[2];
#pragma unroll
      for (int mf = 0; mf < 4; ++mf)
        af[mf] = *reinterpret_cast<const bf16x8*>(&Al[(wr * 64 + mf * 16 + cpr) * 40 + g * 8]);
#pragma unroll
      for (int nf = 0; nf < 2; ++nf)
        bfr[nf] = *reinterpret_cast<const bf16x8*>(&Bl[(wc * 32 + nf * 16 + cpr) * 40 + g * 8]);
#pragma unroll
      for (int mf = 0; mf < 4; ++mf)
#pragma unroll
        for (int nf = 0; nf < 2; ++nf)
          acc[mf][nf] = MFMA(af[mf], bfr[nf], acc[mf][nf]);
      __syncthreads();
    }
#pragma unroll
    for (int mf = 0; mf < 4; ++mf) {
      int m0 = wr * 64 + mf * 16 + g * 4;
#pragma unroll
      for (int nf = 0; nf < 2; ++nf) {
        int nl = wc * 32 + nf * 16 + cpr;
        union { short s[4]; uint2 u; } pk;
#pragma unroll
        for (int r = 0; r < 4; ++r) {
          int c = m0 + r;
          float z = acc[mf][nf][r] * bnc[c] + bnc[128 + c];
          pk.s[r] = f2b(z / (1.f + __expf(-z)));
        }
        *reinterpret_cast<uint2*>(&X1[nl * 136 + m0]) = pk.u;
      }
    }
  }
  __syncthreads();

  for (int which = 0; which < 3; ++which) {
    const short* W = which == 0 ? wvb : which == 1 ? wkb : wqb;
    const float* bias = which == 0 ? bv : which == 1 ? bk : bq;
    f32x4 acc[4][2] = {};
    for (int kk = 0; kk < 4; ++kk) {
#pragma unroll
      for (int it = 0; it < 2; ++it) {
        int f = tid + it * 256;
        int row = f >> 2, c8 = f & 3;
        *reinterpret_cast<uint4*>(&Al[row * 40 + c8 * 8]) =
            *reinterpret_cast<const uint4*>(&W[row * 128 + kk * 32 + c8 * 8]);
      }
      __syncthreads();
      bf16x8 af[4], bfr[2];
#pragma unroll
      for (int mf = 0; mf < 4; ++mf)
        af[mf] = *reinterpret_cast<const bf16x8*>(&Al[(wr * 64 + mf * 16 + cpr) * 40 + g * 8]);
#pragma unroll
      for (int nf = 0; nf < 2; ++nf)
        bfr[nf] = *reinterpret_cast<const bf16x8*>(&X1[(wc * 32 + nf * 16 + cpr) * 136 + kk * 32 + g * 8]);
#pragma unroll
      for (int mf = 0; mf < 4; ++mf)
#pragma unroll
        for (int nf = 0; nf < 2; ++nf)
          acc[mf][nf] = MFMA(af[mf], bfr[nf], acc[mf][nf]);
      __syncthreads();
    }
#pragma unroll
    for (int mf = 0; mf < 4; ++mf) {
      int m0 = wr * 64 + mf * 16 + g * 4;
#pragma unroll
      for (int nf = 0; nf < 2; ++nf) {
        int n = n0 + wc * 32 + nf * 16 + cpr;
        int nl = wc * 32 + nf * 16 + cpr;
        if (which == 0) {
#pragma unroll
          for (int r = 0; r < 4; ++r) {
            int c = m0 + r;
            vv[((size_t)b * 128 + c) * 1024 + n] = f2b(acc[mf][nf][r] + bias[c]);
          }
        } else {
          union { short s4[4]; uint2 u; } pk;
#pragma unroll
          for (int r = 0; r < 4; ++r) {
            float v = acc[mf][nf][r] + bias[m0 + r];
            pk.s4[r] = f2b(which == 1 ? v : v * LOG2E);   // q pre-scaled by log2(e)
          }
          if (which == 1) {
            *reinterpret_cast<uint2*>(&kT[((size_t)b * 1024 + n) * 128 + m0]) = pk.u;
          } else {
            *reinterpret_cast<uint2*>(&qT[((size_t)b * 1024 + n) * 128 + m0]) = pk.u;
            *reinterpret_cast<uint2*>(&X1[nl * 136 + m0]) = pk.u;
          }
        }
      }
    }
  }
  __syncthreads();

  {
    const int sel = wid >> 1, nh = wid & 1;
    const short* R = sel ? rwT : rhT;
    float* Og = sel ? Wg : Ug;
    f32x16 d = {};
#pragma unroll
    for (int ks = 0; ks < 8; ++ks) {
      bf16x8 aq = *reinterpret_cast<const bf16x8*>(&X1[(nh * 32 + rl) * 136 + ks * 16 + hi2 * 8]);
      bf16x8 br = *reinterpret_cast<const bf16x8*>(&R[(size_t)rl * 128 + ks * 16 + hi2 * 8]);
      d = MFMA32(aq, br, d);
    }
#pragma unroll
    for (int q2 = 0; q2 < 4; ++q2) {
      f32x4 v4 = { d[4 * q2 + 0], d[4 * q2 + 1], d[4 * q2 + 2], d[4 * q2 + 3] };
      *reinterpret_cast<f32x4*>(&Og[((size_t)b * 32 + rl) * 1024 + n0 + nh * 32 + q2 * 8 + hi2 * 4]) = v4;
    }
  }
}

// ---------------- K2: flash attention (scores in log2 domain, v_exp_f32) + split conv2 ----------------
__launch_bounds__(256, 2)
__global__ void k_attn(const short* __restrict__ qT, const short* __restrict__ kT,
                       const short* __restrict__ vv, const float* __restrict__ Ug,
                       const float* __restrict__ Wg,
                       const short* __restrict__ w2b, const float* __restrict__ bnc,
                       const float* __restrict__ x, float* __restrict__ out) {
  __shared__ __align__(16) char smem[66560];
  short* KhB0 = (short*)smem;                      // 16K
  short* KhB1 = (short*)(smem + 16384);            // 16K
  short* VtB0 = (short*)(smem + 32768);            // 16K
  short* VtB1 = (short*)(smem + 49152);            // 16K
  uint16_t* ObufB0 = (uint16_t*)smem;              // epilogue: [64][128] bf16 swizzled (16K)
  uint16_t* ObufB1 = (uint16_t*)(smem + 16384);    // epilogue: 16K
  float*    mlf    = (float*)(smem + 32768);       // epilogue: 1K

  const int bx0 = blockIdx.x;
  const int lbx = ((bx0 & 7) << 6) | (bx0 >> 3);   // bijective XCD swizzle (512 = 8*64)
  const int b  = lbx >> 4;
  const int i0 = (lbx & 15) << 6;
  const int tid = threadIdx.x;
  const int wid = tid >> 6, lane = tid & 63;
  const int rl = lane & 31, hi = lane >> 5;
  const int jh = wid >> 1, iq = wid & 1;
  const size_t bN = (size_t)b * 1024;
  const int hI = ((lbx & 15) << 1) + iq;           // h(i) wave-uniform; w(i) = rl

  const short* srcK[4];
  const short* srcV[4];
#pragma unroll
  for (int it = 0; it < 4; ++it) {
    int gq = it * 256 + tid;
    int row = gq >> 4, p = gq & 15;
    int l = p ^ (row & 7);
    srcK[it] = &kT[(bN + row) * 128 + l * 8];
  }
#pragma unroll
  for (int it = 0; it < 4; ++it) {
    int gq = it * 256 + tid;
    int c = gq >> 3, p = gq & 7;
    int l = p ^ (c & 7);
    srcV[it] = &vv[((size_t)b * 128 + c) * 1024 + l * 8];
  }
#pragma unroll
  for (int it = 0; it < 4; ++it) glds16(srcK[it], &KhB0[(it * 256 + wid * 64) * 8]);
#pragma unroll
  for (int it = 0; it < 4; ++it) glds16(srcV[it], &VtB0[(it * 256 + wid * 64) * 8]);

  bf16x8 qf[8];
  {
    const int irow = i0 + iq * 32 + rl;
#pragma unroll
    for (int ks = 0; ks < 8; ++ks)
      qf[ks] = *reinterpret_cast<const bf16x8*>(&qT[(bN + irow) * 128 + ks * 16 + hi * 8]);
  }
  __syncthreads();

  f32x16 oacc[4] = {};
  float mrow = -3e38f, lrow = 0.f;
  const float* Urow = &Ug[((size_t)b * 32 + hI) * 1024 + (jh << 5) + (hi << 2)];
  const float* Wrow = &Wg[((size_t)b * 32 + rl) * 1024 + (jh << 5) + (hi << 2)];

  for (int jt = 0; jt < 16; ++jt) {
    const int cur = jt & 1;
    f32x4 u4[4], w4[4];
#pragma unroll
    for (int g2 = 0; g2 < 4; ++g2) {
      u4[g2] = *reinterpret_cast<const f32x4*>(&Urow[(jt << 6) + g2 * 8]);
      w4[g2] = *reinterpret_cast<const f32x4*>(&Wrow[(jt << 6) + g2 * 8]);
    }
    if (jt < 15) {
      short* KhN = cur ? KhB0 : KhB1;
      short* VtN = cur ? VtB0 : VtB1;
#pragma unroll
      for (int it = 0; it < 4; ++it)
        glds16(srcK[it] + ((jt + 1) << 13), &KhN[(it * 256 + wid * 64) * 8]);
#pragma unroll
      for (int it = 0; it < 4; ++it)
        glds16(srcV[it] + ((jt + 1) << 6), &VtN[(it * 256 + wid * 64) * 8]);
    }
    const short* KhC = cur ? KhB1 : KhB0;
    const short* VtC = cur ? VtB1 : VtB0;

    f32x16 s0 = {}, s1 = {};
    {
      const int rb = (jh * 32 + rl) * 128;
      __builtin_amdgcn_s_setprio(1);
#pragma unroll
      for (int ks = 0; ks < 8; ++ks) {
        int p = ((ks << 1) | hi) ^ (rl & 7);
        bf16x8 kf = *reinterpret_cast<const bf16x8*>(&KhC[rb + p * 8]);
        if (ks & 1) s1 = MFMA32(kf, qf[ks], s1);
        else        s0 = MFMA32(kf, qf[ks], s0);
      }
      __builtin_amdgcn_s_setprio(0);
    }
    float t[16];
#pragma unroll
    for (int r = 0; r < 16; ++r)
      t[r] = s0[r] + s1[r] + u4[r >> 2][r & 3] + w4[r >> 2][r & 3];
    float mx = t[0];
#pragma unroll
    for (int r = 1; r < 16; ++r) mx = fmaxf(mx, t[r]);
    mx = fmaxf(mx, __shfl_xor(mx, 32));
    float pr[16];
    float ps = 0.f;
    if (__all(mx <= mrow + 11.5416f)) {   // defer-max (8*log2e in log2 domain)
#pragma unroll
      for (int r = 0; r < 16; ++r) { pr[r] = fexp2(t[r] - mrow); ps += pr[r]; }
      ps += __shfl_xor(ps, 32);
      lrow += ps;
    } else {
      float mnew = fmaxf(mrow, mx);
      float sc = fexp2(mrow - mnew);
#pragma unroll
      for (int r = 0; r < 16; ++r) { pr[r] = fexp2(t[r] - mnew); ps += pr[r]; }
      ps += __shfl_xor(ps, 32);
      lrow = lrow * sc + ps;
      mrow = mnew;
#pragma unroll
      for (int ct = 0; ct < 4; ++ct)
#pragma unroll
        for (int r = 0; r < 16; ++r) oacc[ct][r] *= sc;
    }
    uint32_t own[8], rcv[8];
#pragma unroll
    for (int idx = 0; idx < 8; ++idx) own[idx] = cvtpk(pr[2 * idx], pr[2 * idx + 1]);
#pragma unroll
    for (int idx = 0; idx < 8; ++idx) rcv[idx] = __shfl_xor((int)own[idx], 32);
#pragma unroll
    for (int js = 0; js < 2; ++js) {
      union { uint32_t u[4]; bf16x8 v; } pa;
      pa.u[0] = hi ? rcv[4 * js + 2] : own[4 * js + 0];
      pa.u[1] = hi ? rcv[4 * js + 3] : own[4 * js + 1];
      pa.u[2] = hi ? own[4 * js + 2] : rcv[4 * js + 0];
      pa.u[3] = hi ? own[4 * js + 3] : rcv[4 * js + 1];
      __builtin_amdgcn_s_setprio(1);
#pragma unroll
      for (int ct = 0; ct < 4; ++ct) {
        int c = ct * 32 + rl;
        int p = ((jh << 2) | (js << 1) | hi) ^ (rl & 7);
        bf16x8 vf = *reinterpret_cast<const bf16x8*>(&VtC[c * 64 + p * 8]);
        oacc[ct] = MFMA32(vf, pa.v, oacc[ct]);
      }
      __builtin_amdgcn_s_setprio(0);
    }
    __syncthreads();
  }

  // ---- merge m/l only (O halves stay separate; conv2 is linear) ----
  if (lane < 32) {
    mlf[wid * 64 + rl]      = mrow;
    mlf[wid * 64 + 32 + rl] = lrow;
  }
  __syncthreads();
  float scl;
  {
    const int pid = wid ^ 2;
    float mp = mlf[pid * 64 + rl];
    float lp = mlf[pid * 64 + 32 + rl];
    float M  = fmaxf(mrow, mp);
    float f  = fexp2(mrow - M);
    float fp = fexp2(mp - M);
    scl = f / (lrow * f + lp * fp);
  }
  bf16x8 af2[2][8];
#pragma unroll
  for (int sub = 0; sub < 2; ++sub)
#pragma unroll
    for (int ks = 0; ks < 8; ++ks)
      af2[sub][ks] = *reinterpret_cast<const bf16x8*>(
          &w2b[(size_t)(wid * 64 + sub * 32 + rl) * 128 + ks * 16 + hi * 8]);
  __syncthreads();

  {
    uint32_t* OW = (uint32_t*)(jh ? ObufB1 : ObufB0);
    const int row = iq * 32 + rl;
#pragma unroll
    for (int ct = 0; ct < 4; ++ct) {
#pragma unroll
      for (int m = 0; m < 8; ++m) {
        int c0 = ct * 32 + ((2 * m) & 3) + 8 * ((2 * m) >> 2) + 4 * hi;
        int gI = c0 >> 3, wo = (c0 & 7) >> 1;
        int gS = gI ^ (row & 15);
        OW[row * 64 + gS * 4 + wo] = cvtpk(oacc[ct][2 * m] * scl, oacc[ct][2 * m + 1] * scl);
      }
    }
  }
  __syncthreads();

  f32x16 a2[2][2] = {};
#pragma unroll
  for (int it = 0; it < 2; ++it) {
    const int r2 = it * 32 + rl;
    __builtin_amdgcn_s_setprio(1);
#pragma unroll
    for (int ks = 0; ks < 8; ++ks) {
      int gS = ((ks << 1) | hi) ^ (r2 & 15);
      bf16x8 bf0 = *reinterpret_cast<const bf16x8*>(&ObufB0[r2 * 128 + gS * 8]);
      bf16x8 bf1 = *reinterpret_cast<const bf16x8*>(&ObufB1[r2 * 128 + gS * 8]);
      a2[0][it] = MFMA32(af2[0][ks], bf0, a2[0][it]);
      a2[1][it] = MFMA32(af2[1][ks], bf0, a2[1][it]);
      a2[0][it] = MFMA32(af2[0][ks], bf1, a2[0][it]);
      a2[1][it] = MFMA32(af2[1][ks], bf1, a2[1][it]);
    }
    __builtin_amdgcn_s_setprio(0);
  }
#pragma unroll
  for (int sub = 0; sub < 2; ++sub) {
    float bsc[16], bsh[16];
#pragma unroll
    for (int r = 0; r < 16; ++r) {
      int co = wid * 64 + sub * 32 + (r & 3) + 8 * (r >> 2) + 4 * hi;
      bsc[r] = bnc[256 + co];
      bsh[r] = bnc[512 + co];
    }
#pragma unroll
    for (int it = 0; it < 2; ++it) {
#pragma unroll
      for (int r = 0; r < 16; ++r) {
        int co = wid * 64 + sub * 32 + (r & 3) + 8 * (r >> 2) + 4 * hi;
        size_t idx = ((size_t)b * 256 + co) * 1024 + i0 + it * 32 + rl;
        float y = a2[sub][it][r] * bsc[r] + bsh[r];
        out[idx] = x[idx] + y / (1.f + __expf(-y));
      }
    }
  }
}

// ---------------- host ----------------
extern "C" void kernel_launch(void* const* d_in, const int* in_sizes, int n_in,
                              void* d_out, int out_size, void* d_ws, size_t ws_size,
                              hipStream_t stream) {
  (void)in_sizes; (void)n_in; (void)out_size; (void)ws_size;
  const float* x    = (const float*)d_in[0];
  const float* w1   = (const float*)d_in[1];
  const float* g1   = (const float*)d_in[2];
  const float* b1   = (const float*)d_in[3];
  const float* m1   = (const float*)d_in[4];
  const float* v1   = (const float*)d_in[5];
  const float* wq   = (const float*)d_in[6];
  const float* bq   = (const float*)d_in[7];
  const float* wk   = (const float*)d_in[8];
  const float* bk   = (const float*)d_in[9];
  const float* wv   = (const float*)d_in[10];
  const float* bv   = (const float*)d_in[11];
  const float* relh = (const float*)d_in[12];
  const float* relw = (const float*)d_in[13];
  const float* w2   = (const float*)d_in[14];
  const float* g2   = (const float*)d_in[15];
  const float* b2   = (const float*)d_in[16];
  const float* m2   = (const float*)d_in[17];
  const float* v2   = (const float*)d_in[18];
  float* out = (float*)d_out;

  char* ws = (char*)d_ws;
  const size_t OFF_W1B  = 0;
  const size_t OFF_WQB  = 65536;
  const size_t OFF_WKB  = 98304;
  const size_t OFF_WVB  = 131072;
  const size_t OFF_W2B  = 163840;
  const size_t OFF_RHT  = 229376;
  const size_t OFF_RWT  = 237568;
  const size_t OFF_BN   = 491520;
  const size_t OFF_QT   = 494592;
  const size_t OFF_KT   = OFF_QT + 8388608;
  const size_t OFF_V    = OFF_KT + 8388608;
  const size_t OFF_UG   = OFF_V + 8388608;
  const size_t OFF_WG   = OFF_UG + 4194304;

  short* w1b  = (short*)(ws + OFF_W1B);
  short* wqb  = (short*)(ws + OFF_WQB);
  short* wkb  = (short*)(ws + OFF_WKB);
  short* wvb  = (short*)(ws + OFF_WVB);
  short* w2b  = (short*)(ws + OFF_W2B);
  short* rhT  = (short*)(ws + OFF_RHT);
  short* rwT  = (short*)(ws + OFF_RWT);
  float* bnc  = (float*)(ws + OFF_BN);
  short* qT   = (short*)(ws + OFF_QT);
  short* kT   = (short*)(ws + OFF_KT);
  short* vv   = (short*)(ws + OFF_V);
  float* Ug   = (float*)(ws + OFF_UG);
  float* Wg   = (float*)(ws + OFF_WG);

  k_prep<<<482, 256, 0, stream>>>(w1, wq, wk, wv, w2, relh, relw,
                                  g1, b1, m1, v1, g2, b2, m2, v2,
                                  w1b, wqb, wkb, wvb, w2b, rhT, rwT, bnc);
  k_cq<<<512, 256, 0, stream>>>(x, w1b, wqb, wkb, wvb, bnc, bq, bk, bv,
                                rhT, rwT, qT, kT, vv, Ug, Wg);
  k_attn<<<512, 256, 0, stream>>>(qT, kT, vv, Ug, Wg, w2b, bnc, x, out);
}